// Round 11
// baseline (323.509 us; speedup 1.0000x reference)
//
#include <hip/hip_runtime.h>
#include <hip/hip_cooperative_groups.h>
#include <math.h>

namespace cg = cooperative_groups;

#define RS2f 0.70710678118654752f

typedef __attribute__((ext_vector_type(8))) short bf16x8;
typedef __attribute__((ext_vector_type(4))) float f32x4;

__device__ __forceinline__ unsigned short f2bf(float f) {
    unsigned u = __float_as_uint(f);
    unsigned r = (u + 0x7fffu + ((u >> 16) & 1u)) >> 16;   // RNE
    return (unsigned short)r;
}
__device__ __forceinline__ float bf2f(unsigned short h) {
    return __uint_as_float(((unsigned)h) << 16);
}

// ==================== circuit helpers (R5/R8 structure, 77us local opt) ====================
struct CMat { float m00r,m00i,m01r,m01i,m10r,m10i,m11r,m11i; };

__device__ __forceinline__ CMat mk_rot(const float* __restrict__ qp, int l, int w) {
    const float* g = qp + (l * 12 + w) * 3;
    float phi = g[0], th = g[1], om = g[2];
    float st, ct, sa, ca, sb, cb;
    sincosf(0.5f * th, &st, &ct);
    sincosf(0.5f * (phi + om), &sa, &ca);
    sincosf(0.5f * (phi - om), &sb, &cb);
    CMat M;
    M.m00r =  ct * ca; M.m00i = -ct * sa;
    M.m01r = -st * cb; M.m01i = -st * sb;
    M.m10r =  st * cb; M.m10i = -st * sb;
    M.m11r =  ct * ca; M.m11i =  ct * sa;
    return M;
}

template<int W> struct WI {
    static constexpr int kind = (W == 0 || W == 7) ? 2 : ((W >= 1 && W <= 6) ? 1 : 0);
    static constexpr int eb   = (W >= 8) ? (11 - W) : 0;
    static constexpr int lm   = (W >= 1 && W <= 6) ? (1 << (6 - W)) : 0;
    static constexpr int vm   = (W == 0) ? 2 : ((W == 7) ? 1 : 0);
};

__device__ __forceinline__ void exch_put(float* xbuf, int slot,
                                         const float vr[16], const float vi[16]) {
    __syncthreads();
    float4* p = (float4*)xbuf;
    #pragma unroll
    for (int j = 0; j < 8; ++j)
        p[(j << 8) + slot] = make_float4(vr[2*j], vi[2*j], vr[2*j+1], vi[2*j+1]);
    __syncthreads();
}

__device__ __forceinline__ void shfl_perm(float vr[16], float vi[16], int src) {
    #pragma unroll
    for (int e = 0; e < 16; ++e) {
        vr[e] = __shfl(vr[e], src, 64);
        vi[e] = __shfl(vi[e], src, 64);
    }
}

template<int EB>
__device__ __forceinline__ void rot_local(float vr[16], float vi[16], const CMat& M) {
    #pragma unroll
    for (int e = 0; e < 16; ++e) if (!(e & (1 << EB))) {
        const int e1 = e | (1 << EB);
        float x0r = vr[e],  x0i = vi[e];
        float x1r = vr[e1], x1i = vi[e1];
        vr[e]  = M.m00r*x0r - M.m00i*x0i + M.m01r*x1r - M.m01i*x1i;
        vi[e]  = M.m00r*x0i + M.m00i*x0r + M.m01r*x1i + M.m01i*x1r;
        vr[e1] = M.m10r*x0r - M.m10i*x0i + M.m11r*x1r - M.m11i*x1i;
        vi[e1] = M.m10r*x0i + M.m10i*x0r + M.m11r*x1i + M.m11i*x1r;
    }
}

template<int LM>
__device__ __forceinline__ void rot_lane(float vr[16], float vi[16], int lane, const CMat& M) {
    const bool hi = lane & LM;
    const float Ar = hi ? M.m11r : M.m00r, Ai = hi ? M.m11i : M.m00i;
    const float Br = hi ? M.m10r : M.m01r, Bi = hi ? M.m10i : M.m01i;
    #pragma unroll
    for (int e = 0; e < 16; ++e) {
        float pr = __shfl_xor(vr[e], LM, 64);
        float pi = __shfl_xor(vi[e], LM, 64);
        float orr = vr[e], oi = vi[e];
        vr[e] = Ar*orr - Ai*oi + Br*pr - Bi*pi;
        vi[e] = Ar*oi + Ai*orr + Br*pi + Bi*pr;
    }
}

template<int VM>
__device__ __forceinline__ void rot_wave(float vr[16], float vi[16], float* xbuf,
                                         int waveId, int lane, const CMat& M) {
    exch_put(xbuf, (waveId << 6) + lane, vr, vi);
    const float4* p = (const float4*)xbuf;
    const int ps = ((waveId ^ VM) << 6) + lane;
    const bool hi = waveId & VM;
    const float Ar = hi ? M.m11r : M.m00r, Ai = hi ? M.m11i : M.m00i;
    const float Br = hi ? M.m10r : M.m01r, Bi = hi ? M.m10i : M.m01i;
    #pragma unroll
    for (int j = 0; j < 8; ++j) {
        float4 q = p[(j << 8) + ps];
        const int e0 = 2*j, e1 = 2*j + 1;
        float r0 = vr[e0], i0 = vi[e0], r1 = vr[e1], i1 = vi[e1];
        vr[e0] = Ar*r0 - Ai*i0 + Br*q.x - Bi*q.y;
        vi[e0] = Ar*i0 + Ai*r0 + Br*q.y + Bi*q.x;
        vr[e1] = Ar*r1 - Ai*i1 + Br*q.z - Bi*q.w;
        vi[e1] = Ar*i1 + Ai*r1 + Br*q.w + Bi*q.z;
    }
}

template<int W>
__device__ __forceinline__ void rot_wire(float vr[16], float vi[16], float* xbuf,
                                         int waveId, int lane, const CMat& M) {
    if constexpr (WI<W>::kind == 0)      rot_local<WI<W>::eb>(vr, vi, M);
    else if constexpr (WI<W>::kind == 1) rot_lane<WI<W>::lm>(vr, vi, lane, M);
    else                                 rot_wave<WI<W>::vm>(vr, vi, xbuf, waveId, lane, M);
}

template<int C, int T>
__device__ __forceinline__ void cnot(float vr[16], float vi[16], float* xbuf,
                                     int waveId, int lane) {
    constexpr int ck = WI<C>::kind, tk = WI<T>::kind;
    if constexpr (ck == 0 && tk == 0) {
        constexpr int cb = 1 << WI<C>::eb, tb = 1 << WI<T>::eb;
        #pragma unroll
        for (int e = 0; e < 16; ++e) if ((e & cb) && !(e & tb)) {
            const int e1 = e | tb;
            float t = vr[e]; vr[e] = vr[e1]; vr[e1] = t;
            t = vi[e]; vi[e] = vi[e1]; vi[e1] = t;
        }
    } else if constexpr (ck == 0 && tk == 1) {
        constexpr int cb = 1 << WI<C>::eb, tm = WI<T>::lm;
        #pragma unroll
        for (int e = 0; e < 16; ++e) if (e & cb) {
            vr[e] = __shfl_xor(vr[e], tm, 64);
            vi[e] = __shfl_xor(vi[e], tm, 64);
        }
    } else if constexpr (ck == 0 && tk == 2) {
        constexpr int cb = 1 << WI<C>::eb, vm = WI<T>::vm;
        exch_put(xbuf, (waveId << 6) + lane, vr, vi);
        const float4* p = (const float4*)xbuf;
        const int ps = ((waveId ^ vm) << 6) + lane;
        #pragma unroll
        for (int j = 0; j < 8; ++j) {
            if ((((2*j) & cb) != 0) || (((2*j+1) & cb) != 0)) {
                float4 q = p[(j << 8) + ps];
                if (((2*j) & cb) != 0)   { vr[2*j]   = q.x; vi[2*j]   = q.y; }
                if (((2*j+1) & cb) != 0) { vr[2*j+1] = q.z; vi[2*j+1] = q.w; }
            }
        }
    } else if constexpr (ck == 1 && tk == 0) {
        constexpr int cm = WI<C>::lm, tb = 1 << WI<T>::eb;
        const bool cc = lane & cm;
        #pragma unroll
        for (int e = 0; e < 16; ++e) if (!(e & tb)) {
            const int e1 = e | tb;
            float a = vr[e], bb = vr[e1];
            vr[e] = cc ? bb : a; vr[e1] = cc ? a : bb;
            a = vi[e]; bb = vi[e1];
            vi[e] = cc ? bb : a; vi[e1] = cc ? a : bb;
        }
    } else if constexpr (ck == 1 && tk == 1) {
        constexpr int cm = WI<C>::lm, tm = WI<T>::lm;
        const int src = (lane & cm) ? (lane ^ tm) : lane;
        shfl_perm(vr, vi, src);
    } else if constexpr (ck == 1 && tk == 2) {
        constexpr int cm = WI<C>::lm, vm = WI<T>::vm;
        exch_put(xbuf, (waveId << 6) + lane, vr, vi);
        const float4* p = (const float4*)xbuf;
        const int ps = ((waveId ^ vm) << 6) + lane;
        const bool take = lane & cm;
        #pragma unroll
        for (int j = 0; j < 8; ++j) {
            float4 q = p[(j << 8) + ps];
            vr[2*j]   = take ? q.x : vr[2*j];   vi[2*j]   = take ? q.y : vi[2*j];
            vr[2*j+1] = take ? q.z : vr[2*j+1]; vi[2*j+1] = take ? q.w : vi[2*j+1];
        }
    } else if constexpr (ck == 2 && tk == 0) {
        constexpr int vm = WI<C>::vm, tb = 1 << WI<T>::eb;
        if (waveId & vm) {
            #pragma unroll
            for (int e = 0; e < 16; ++e) if (!(e & tb)) {
                const int e1 = e | tb;
                float t = vr[e]; vr[e] = vr[e1]; vr[e1] = t;
                t = vi[e]; vi[e] = vi[e1]; vi[e1] = t;
            }
        }
    } else {
        constexpr int vm = WI<C>::vm, tm = WI<T>::lm;
        if (waveId & vm) {
            #pragma unroll
            for (int e = 0; e < 16; ++e) {
                vr[e] = __shfl_xor(vr[e], tm, 64);
                vi[e] = __shfl_xor(vi[e], tm, 64);
            }
        }
    }
}

template<int W>
__device__ __forceinline__ void h_wire(float vr[16], float vi[16], float* xbuf,
                                       int waveId, int lane) {
    if constexpr (WI<W>::kind == 0) {
        constexpr int tb = 1 << WI<W>::eb;
        #pragma unroll
        for (int e = 0; e < 16; ++e) if (!(e & tb)) {
            const int e1 = e | tb;
            float x0 = vr[e], x1 = vr[e1];
            vr[e] = (x0 + x1) * RS2f; vr[e1] = (x0 - x1) * RS2f;
            x0 = vi[e]; x1 = vi[e1];
            vi[e] = (x0 + x1) * RS2f; vi[e1] = (x0 - x1) * RS2f;
        }
    } else if constexpr (WI<W>::kind == 1) {
        constexpr int m = WI<W>::lm;
        const float sgn = (lane & m) ? -RS2f : RS2f;
        #pragma unroll
        for (int e = 0; e < 16; ++e) {
            float pr = __shfl_xor(vr[e], m, 64);
            float pi = __shfl_xor(vi[e], m, 64);
            vr[e] = pr * RS2f + vr[e] * sgn;
            vi[e] = pi * RS2f + vi[e] * sgn;
        }
    } else {
        constexpr int vm = WI<W>::vm;
        exch_put(xbuf, (waveId << 6) + lane, vr, vi);
        const float4* p = (const float4*)xbuf;
        const int ps = ((waveId ^ vm) << 6) + lane;
        const float sgn = (waveId & vm) ? -RS2f : RS2f;
        #pragma unroll
        for (int j = 0; j < 8; ++j) {
            float4 q = p[(j << 8) + ps];
            vr[2*j]   = q.x * RS2f + vr[2*j]   * sgn;
            vi[2*j]   = q.y * RS2f + vi[2*j]   * sgn;
            vr[2*j+1] = q.z * RS2f + vr[2*j+1] * sgn;
            vi[2*j+1] = q.w * RS2f + vi[2*j+1] * sgn;
        }
    }
}

// ==================================================================
// ONE cooperative kernel: split -> grid.sync -> gemm (512 tiles:
// 64x64, SK=4) -> grid.sync -> circuit (grid-stride over 1024 batch).
// Removes all inter-dispatch gaps and makes the total directly
// measurable as a single dispatch. LDS aliased: gemm As/Bs (18.4 KB)
// live inside the circuit's 32 KB xbuf region; total 40960 B
// (measured: 2 blocks/CU co-resident -> grid 512 = 2/CU).
// ==================================================================
__global__ __launch_bounds__(256) void fused_all(const float* __restrict__ x,
                                                 const float* __restrict__ W,
                                                 const float* __restrict__ bias,
                                                 const float* __restrict__ qp,
                                                 unsigned short* __restrict__ xc,
                                                 unsigned short* __restrict__ wc,
                                                 float* __restrict__ P,
                                                 float* __restrict__ out) {
    __shared__ float smem[10240];        // 40960 B
    float* xbuf = smem;                  // circuit exchange (32 KB)
    float* ang  = smem + 8192;           // circuit angles (8 KB)
    short* As   = (short*)smem;          // gemm A tile (9216 B)
    short* Bs   = (short*)smem + 4608;   // gemm B tile (9216 B)

    const int tid = threadIdx.x;
    const int lane = tid & 63;
    const int waveId = tid >> 6;
    const int nblk = gridDim.x;
    cg::grid_group grid = cg::this_grid();

    // ---------------- phase 1: fp32 -> bf16 hi/lo split ----------------
    for (int idx = blockIdx.x * 256 + tid; idx < 786432; idx += nblk * 256) {
        int i2 = idx;
        const float* src; unsigned short* dst;
        if (i2 < 524288) { src = x; dst = xc; }
        else             { i2 -= 524288; src = W; dst = wc; }
        int m = i2 >> 9;
        int c4 = (i2 & 511) << 2;
        const float4 v = *(const float4*)&src[m * 2048 + c4];
        ushort4 hi, lo;
        hi.x = f2bf(v.x); lo.x = f2bf(v.x - bf2f(hi.x));
        hi.y = f2bf(v.y); lo.y = f2bf(v.y - bf2f(hi.y));
        hi.z = f2bf(v.z); lo.z = f2bf(v.z - bf2f(hi.z));
        hi.w = f2bf(v.w); lo.w = f2bf(v.w - bf2f(hi.w));
        *(ushort4*)&dst[m * 4096 + c4] = hi;
        *(ushort4*)&dst[m * 4096 + 2048 + c4] = lo;
    }
    __threadfence();
    grid.sync();

    // ---------------- phase 2: MFMA GEMM partials, SK=4 ----------------
    // tile t: m0=(t&15)*64, n0=((t>>4)&7)*64, z=t>>7; nch=16, kb=z*1024
    for (int t = blockIdx.x; t < 512; t += nblk) {
        const int m0 = (t & 15) * 64, n0 = ((t >> 4) & 7) * 64, z = t >> 7;
        const int kb = z * 1024;
        const int quad = lane >> 4, mrow = lane & 15;
        const int srow = tid >> 2;
        const int sk = (tid & 3) * 16;
        const unsigned short* Arow = xc + (size_t)(m0 + srow) * 4096 + kb + sk;
        const unsigned short* Brow = wc + (size_t)(n0 + srow) * 4096 + kb + sk;
        f32x4 acc[4];
        #pragma unroll
        for (int j = 0; j < 4; ++j) acc[j] = (f32x4){0.f, 0.f, 0.f, 0.f};
        float4 a0 = *(const float4*)Arow;
        float4 a1 = *(const float4*)(Arow + 8);
        float4 b0 = *(const float4*)Brow;
        float4 b1 = *(const float4*)(Brow + 8);
        for (int ch = 0; ch < 16; ++ch) {
            __syncthreads();
            *(float4*)&As[srow * 72 + sk]     = a0;
            *(float4*)&As[srow * 72 + sk + 8] = a1;
            *(float4*)&Bs[srow * 72 + sk]     = b0;
            *(float4*)&Bs[srow * 72 + sk + 8] = b1;
            __syncthreads();
            if (ch + 1 < 16) {
                const int o = (ch + 1) * 64;
                a0 = *(const float4*)(Arow + o);
                a1 = *(const float4*)(Arow + o + 8);
                b0 = *(const float4*)(Brow + o);
                b1 = *(const float4*)(Brow + o + 8);
            }
            #pragma unroll
            for (int ks = 0; ks < 2; ++ks) {
                bf16x8 af = *(const bf16x8*)&As[(waveId * 16 + mrow) * 72 + ks * 32 + quad * 8];
                #pragma unroll
                for (int j = 0; j < 4; ++j) {
                    bf16x8 bf = *(const bf16x8*)&Bs[(j * 16 + mrow) * 72 + ks * 32 + quad * 8];
                    acc[j] = __builtin_amdgcn_mfma_f32_16x16x32_bf16(af, bf, acc[j], 0, 0, 0);
                }
            }
        }
        float* Pz = P + (size_t)z * 524288;
        #pragma unroll
        for (int j = 0; j < 4; ++j)
            #pragma unroll
            for (int r = 0; r < 4; ++r)
                Pz[(m0 + waveId * 16 + quad * 4 + r) * 512 + n0 + j * 16 + mrow] = acc[j][r];
        __syncthreads();               // protect As/Bs reuse across t-iterations
    }
    __threadfence();
    grid.sync();

    // ---------------- phase 3: circuit, grid-stride over batch ----------------
    for (int b = blockIdx.x; b < 1024; b += nblk) {
        __syncthreads();               // protect smem reuse across b-iterations

        // fused reduce: com row = bias + sum of 4 partial slabs
        if (tid < 128) {
            float4 s = ((const float4*)bias)[tid];
            #pragma unroll
            for (int z = 0; z < 4; ++z) {
                float4 p4 = *(const float4*)&P[(size_t)z * 524288 + b * 512 + tid * 4];
                s.x += p4.x; s.y += p4.y; s.z += p4.z; s.w += p4.w;
            }
            ((float4*)ang)[tid] = s;
        }
        __syncthreads();

        float vr[16], vi[16];
        #pragma unroll
        for (int e = 0; e < 16; ++e) { vr[e] = 0.0f; vi[e] = 0.0f; }

        const float K9 = 0.044194173824159216f;   // 2^-4.5
        #pragma unroll
        for (int m = 0; m < 4; ++m) {
            int j = (lane << 3) | ((waveId & 1) << 2) | m;
            int rj = (int)(__brev((unsigned)j) >> 23);
            float s, c;
            sincosf(0.5f * ang[rj], &s, &c);
            vr[m << 2] = K9 * ((waveId & 2) ? s : c);
        }

        #pragma unroll 1
        for (int l = 0; l < 2; ++l) {
            { CMat M = mk_rot(qp, l, 0);  rot_wire<0 >(vr, vi, xbuf, waveId, lane, M); }
            { CMat M = mk_rot(qp, l, 1);  rot_wire<1 >(vr, vi, xbuf, waveId, lane, M); }
            { CMat M = mk_rot(qp, l, 2);  rot_wire<2 >(vr, vi, xbuf, waveId, lane, M); }
            { CMat M = mk_rot(qp, l, 3);  rot_wire<3 >(vr, vi, xbuf, waveId, lane, M); }
            { CMat M = mk_rot(qp, l, 4);  rot_wire<4 >(vr, vi, xbuf, waveId, lane, M); }
            { CMat M = mk_rot(qp, l, 5);  rot_wire<5 >(vr, vi, xbuf, waveId, lane, M); }
            { CMat M = mk_rot(qp, l, 6);  rot_wire<6 >(vr, vi, xbuf, waveId, lane, M); }
            { CMat M = mk_rot(qp, l, 7);  rot_wire<7 >(vr, vi, xbuf, waveId, lane, M); }
            { CMat M = mk_rot(qp, l, 8);  rot_wire<8 >(vr, vi, xbuf, waveId, lane, M); }
            { CMat M = mk_rot(qp, l, 9);  rot_wire<9 >(vr, vi, xbuf, waveId, lane, M); }
            { CMat M = mk_rot(qp, l, 10); rot_wire<10>(vr, vi, xbuf, waveId, lane, M); }
            { CMat M = mk_rot(qp, l, 11); rot_wire<11>(vr, vi, xbuf, waveId, lane, M); }
            if (l == 0) {                 // r = 1
                int j = lane;
                j ^= (j & 2)  ? 1  : 0;           // C(5,6)
                j ^= (j & 4)  ? 2  : 0;           // C(4,5)
                j ^= (j & 8)  ? 4  : 0;           // C(3,4)
                j ^= (j & 16) ? 8  : 0;           // C(2,3)
                j ^= (j & 32) ? 16 : 0;           // C(1,2)
                j ^= (waveId & 2) ? 32 : 0;       // C(0,1)
                shfl_perm(vr, vi, j);
                cnot<6,7>(vr,vi,xbuf,waveId,lane);   cnot<7,8>(vr,vi,xbuf,waveId,lane);
                cnot<8,9>(vr,vi,xbuf,waveId,lane);   cnot<9,10>(vr,vi,xbuf,waveId,lane);
                cnot<10,11>(vr,vi,xbuf,waveId,lane); cnot<11,0>(vr,vi,xbuf,waveId,lane);
            } else {                      // r = 2
                int j = lane;
                j ^= (j & 4)  ? 1  : 0;           // C(4,6)
                j ^= (j & 8)  ? 2  : 0;           // C(3,5)
                j ^= (j & 16) ? 4  : 0;           // C(2,4)
                j ^= (j & 32) ? 8  : 0;           // C(1,3)
                j ^= (waveId & 2) ? 16 : 0;       // C(0,2)
                shfl_perm(vr, vi, j);
                cnot<5,7>(vr,vi,xbuf,waveId,lane);   cnot<6,8>(vr,vi,xbuf,waveId,lane);
                cnot<7,9>(vr,vi,xbuf,waveId,lane);   cnot<8,10>(vr,vi,xbuf,waveId,lane);
                cnot<9,11>(vr,vi,xbuf,waveId,lane);  cnot<10,0>(vr,vi,xbuf,waveId,lane);
                cnot<11,1>(vr,vi,xbuf,waveId,lane);
            }
        }

        h_wire<1>(vr,vi,xbuf,waveId,lane);  h_wire<2>(vr,vi,xbuf,waveId,lane);
        h_wire<3>(vr,vi,xbuf,waveId,lane);  h_wire<4>(vr,vi,xbuf,waveId,lane);
        h_wire<5>(vr,vi,xbuf,waveId,lane);  h_wire<6>(vr,vi,xbuf,waveId,lane);
        h_wire<7>(vr,vi,xbuf,waveId,lane);  h_wire<8>(vr,vi,xbuf,waveId,lane);
        h_wire<9>(vr,vi,xbuf,waveId,lane);  h_wire<10>(vr,vi,xbuf,waveId,lane);
        h_wire<11>(vr,vi,xbuf,waveId,lane);

        {
            const float4* x4 = (const float4*)(x + b * 2048);
            ((float4*)ang)[tid]       = x4[tid];
            ((float4*)ang)[tid + 256] = x4[tid + 256];
        }
        __syncthreads();

        exch_put(xbuf, (waveId << 6) + lane, vr, vi);
        {
            const float4* p = (const float4*)xbuf;
            const int ps = ((waveId ^ 2) << 6) + lane;
            const bool hi = waveId & 2;
            float acc = 0.0f;
            #pragma unroll
            for (int j = 0; j < 8; ++j) {
                float4 q = p[(j << 8) + ps];
                #pragma unroll
                for (int h = 0; h < 2; ++h) {
                    const int e = 2*j + h;
                    const float prr = h ? q.z : q.x;
                    const float pii = h ? q.w : q.y;
                    int v = (lane << 5) | ((waveId & 1) << 4) | e;
                    int rv = (int)(__brev((unsigned)v) >> 21);
                    float s, c;
                    sincosf(0.5f * ang[rv], &s, &c);
                    float nr = hi ? (s*prr + c*vr[e]) : (c*vr[e] - s*prr);
                    float ni = hi ? (s*pii + c*vi[e]) : (c*vi[e] - s*pii);
                    acc += nr*nr + ni*ni;
                }
            }
            if (!hi) acc = -acc;
            #pragma unroll
            for (int off = 32; off > 0; off >>= 1) acc += __shfl_down(acc, off, 64);
            __syncthreads();
            if (lane == 0) xbuf[waveId] = acc;
            __syncthreads();
            if (tid == 0) out[b] = xbuf[0] + xbuf[1] + xbuf[2] + xbuf[3];
        }
    }
}

// ==================== fallback path (small ws): fp32 GEMM + circuit ====================
__global__ __launch_bounds__(256) void gemm_f32(const float* __restrict__ A,
                                                const float* __restrict__ W,
                                                const float* __restrict__ bias,
                                                float* __restrict__ C) {
    __shared__ float Asf[64][33];
    __shared__ float Bsf[32][33];
    const int tid = threadIdx.x;
    const int m0 = blockIdx.x * 64;
    const int n0 = blockIdx.y * 32;
    const int tm = tid >> 4, tn = tid & 15;
    float acc[4][2] = {};
    for (int k0 = 0; k0 < 2048; k0 += 32) {
        #pragma unroll
        for (int i = 0; i < 8; ++i) {
            int idx = tid + i * 256;
            Asf[idx >> 5][idx & 31] = A[(m0 + (idx >> 5)) * 2048 + k0 + (idx & 31)];
        }
        #pragma unroll
        for (int i = 0; i < 4; ++i) {
            int idx = tid + i * 256;
            Bsf[idx >> 5][idx & 31] = W[(n0 + (idx >> 5)) * 2048 + k0 + (idx & 31)];
        }
        __syncthreads();
        #pragma unroll
        for (int kk = 0; kk < 32; ++kk) {
            float a0 = Asf[tm*4+0][kk], a1 = Asf[tm*4+1][kk];
            float a2 = Asf[tm*4+2][kk], a3 = Asf[tm*4+3][kk];
            float b0 = Bsf[tn*2+0][kk], b1 = Bsf[tn*2+1][kk];
            acc[0][0] += a0*b0; acc[0][1] += a0*b1;
            acc[1][0] += a1*b0; acc[1][1] += a1*b1;
            acc[2][0] += a2*b0; acc[2][1] += a2*b1;
            acc[3][0] += a3*b0; acc[3][1] += a3*b1;
        }
        __syncthreads();
    }
    #pragma unroll
    for (int r = 0; r < 4; ++r)
        #pragma unroll
        for (int c = 0; c < 2; ++c)
            C[(m0 + tm*4 + r) * 512 + n0 + tn*2 + c] = acc[r][c] + bias[n0 + tn*2 + c];
}

__global__ __launch_bounds__(256) void circuit_sa(const float* __restrict__ com,
                                                  const float* __restrict__ xf,
                                                  const float* __restrict__ qp,
                                                  float* __restrict__ out) {
    __shared__ float smem[10240];
    float* xbuf = smem;
    float* ang  = smem + 8192;
    const int tid = threadIdx.x, lane = tid & 63, waveId = tid >> 6;
    const int b = blockIdx.x;
    if (tid < 128) ((float4*)ang)[tid] = ((const float4*)(com + b * 512))[tid];
    __syncthreads();
    float vr[16], vi[16];
    #pragma unroll
    for (int e = 0; e < 16; ++e) { vr[e] = 0.0f; vi[e] = 0.0f; }
    const float K9 = 0.044194173824159216f;
    #pragma unroll
    for (int m = 0; m < 4; ++m) {
        int j = (lane << 3) | ((waveId & 1) << 2) | m;
        int rj = (int)(__brev((unsigned)j) >> 23);
        float s, c;
        sincosf(0.5f * ang[rj], &s, &c);
        vr[m << 2] = K9 * ((waveId & 2) ? s : c);
    }
    #pragma unroll 1
    for (int l = 0; l < 2; ++l) {
        { CMat M = mk_rot(qp, l, 0);  rot_wire<0 >(vr, vi, xbuf, waveId, lane, M); }
        { CMat M = mk_rot(qp, l, 1);  rot_wire<1 >(vr, vi, xbuf, waveId, lane, M); }
        { CMat M = mk_rot(qp, l, 2);  rot_wire<2 >(vr, vi, xbuf, waveId, lane, M); }
        { CMat M = mk_rot(qp, l, 3);  rot_wire<3 >(vr, vi, xbuf, waveId, lane, M); }
        { CMat M = mk_rot(qp, l, 4);  rot_wire<4 >(vr, vi, xbuf, waveId, lane, M); }
        { CMat M = mk_rot(qp, l, 5);  rot_wire<5 >(vr, vi, xbuf, waveId, lane, M); }
        { CMat M = mk_rot(qp, l, 6);  rot_wire<6 >(vr, vi, xbuf, waveId, lane, M); }
        { CMat M = mk_rot(qp, l, 7);  rot_wire<7 >(vr, vi, xbuf, waveId, lane, M); }
        { CMat M = mk_rot(qp, l, 8);  rot_wire<8 >(vr, vi, xbuf, waveId, lane, M); }
        { CMat M = mk_rot(qp, l, 9);  rot_wire<9 >(vr, vi, xbuf, waveId, lane, M); }
        { CMat M = mk_rot(qp, l, 10); rot_wire<10>(vr, vi, xbuf, waveId, lane, M); }
        { CMat M = mk_rot(qp, l, 11); rot_wire<11>(vr, vi, xbuf, waveId, lane, M); }
        if (l == 0) {
            int j = lane;
            j ^= (j & 2)  ? 1  : 0;  j ^= (j & 4)  ? 2  : 0;
            j ^= (j & 8)  ? 4  : 0;  j ^= (j & 16) ? 8  : 0;
            j ^= (j & 32) ? 16 : 0;  j ^= (waveId & 2) ? 32 : 0;
            shfl_perm(vr, vi, j);
            cnot<6,7>(vr,vi,xbuf,waveId,lane);   cnot<7,8>(vr,vi,xbuf,waveId,lane);
            cnot<8,9>(vr,vi,xbuf,waveId,lane);   cnot<9,10>(vr,vi,xbuf,waveId,lane);
            cnot<10,11>(vr,vi,xbuf,waveId,lane); cnot<11,0>(vr,vi,xbuf,waveId,lane);
        } else {
            int j = lane;
            j ^= (j & 4)  ? 1  : 0;  j ^= (j & 8)  ? 2  : 0;
            j ^= (j & 16) ? 4  : 0;  j ^= (j & 32) ? 8  : 0;
            j ^= (waveId & 2) ? 16 : 0;
            shfl_perm(vr, vi, j);
            cnot<5,7>(vr,vi,xbuf,waveId,lane);   cnot<6,8>(vr,vi,xbuf,waveId,lane);
            cnot<7,9>(vr,vi,xbuf,waveId,lane);   cnot<8,10>(vr,vi,xbuf,waveId,lane);
            cnot<9,11>(vr,vi,xbuf,waveId,lane);  cnot<10,0>(vr,vi,xbuf,waveId,lane);
            cnot<11,1>(vr,vi,xbuf,waveId,lane);
        }
    }
    h_wire<1>(vr,vi,xbuf,waveId,lane);  h_wire<2>(vr,vi,xbuf,waveId,lane);
    h_wire<3>(vr,vi,xbuf,waveId,lane);  h_wire<4>(vr,vi,xbuf,waveId,lane);
    h_wire<5>(vr,vi,xbuf,waveId,lane);  h_wire<6>(vr,vi,xbuf,waveId,lane);
    h_wire<7>(vr,vi,xbuf,waveId,lane);  h_wire<8>(vr,vi,xbuf,waveId,lane);
    h_wire<9>(vr,vi,xbuf,waveId,lane);  h_wire<10>(vr,vi,xbuf,waveId,lane);
    h_wire<11>(vr,vi,xbuf,waveId,lane);
    {
        const float4* x4 = (const float4*)(xf + b * 2048);
        ((float4*)ang)[tid]       = x4[tid];
        ((float4*)ang)[tid + 256] = x4[tid + 256];
    }
    __syncthreads();
    exch_put(xbuf, (waveId << 6) + lane, vr, vi);
    {
        const float4* p = (const float4*)xbuf;
        const int ps = ((waveId ^ 2) << 6) + lane;
        const bool hi = waveId & 2;
        float acc = 0.0f;
        #pragma unroll
        for (int j = 0; j < 8; ++j) {
            float4 q = p[(j << 8) + ps];
            #pragma unroll
            for (int h = 0; h < 2; ++h) {
                const int e = 2*j + h;
                const float prr = h ? q.z : q.x;
                const float pii = h ? q.w : q.y;
                int v = (lane << 5) | ((waveId & 1) << 4) | e;
                int rv = (int)(__brev((unsigned)v) >> 21);
                float s, c;
                sincosf(0.5f * ang[rv], &s, &c);
                float nr = hi ? (s*prr + c*vr[e]) : (c*vr[e] - s*prr);
                float ni = hi ? (s*pii + c*vi[e]) : (c*vi[e] - s*pii);
                acc += nr*nr + ni*ni;
            }
        }
        if (!hi) acc = -acc;
        #pragma unroll
        for (int off = 32; off > 0; off >>= 1) acc += __shfl_down(acc, off, 64);
        __syncthreads();
        if (lane == 0) xbuf[waveId] = acc;
        __syncthreads();
        if (tid == 0) out[b] = xbuf[0] + xbuf[1] + xbuf[2] + xbuf[3];
    }
}

extern "C" void kernel_launch(void* const* d_in, const int* in_sizes, int n_in,
                              void* d_out, int out_size, void* d_ws, size_t ws_size,
                              hipStream_t stream) {
    const float* x    = (const float*)d_in[0];   // (1024,2048)
    const float* W    = (const float*)d_in[1];   // (512,2048)
    const float* bias = (const float*)d_in[2];   // (512,)
    const float* qp   = (const float*)d_in[3];   // (2,12,3)
    float* out = (float*)d_out;                  // (1024,)

    const size_t MB = 1024ull * 1024;
    int occ = 0;
    (void)hipOccupancyMaxActiveBlocksPerMultiprocessor(&occ, fused_all, 256, 0);

    if (ws_size >= 20 * MB && occ >= 1) {
        // ws: xc 8MB | wc 4MB | P (4 slabs) 8MB
        unsigned short* xc = (unsigned short*)d_ws;
        unsigned short* wc = (unsigned short*)((char*)d_ws + 8 * MB);
        float* P = (float*)((char*)d_ws + 12 * MB);
        int nblk = (occ >= 2) ? 512 : 256;       // all co-resident (256 CUs)
        void* args[] = {(void*)&x, (void*)&W, (void*)&bias, (void*)&qp,
                        (void*)&xc, (void*)&wc, (void*)&P, (void*)&out};
        hipLaunchCooperativeKernel((const void*)fused_all, dim3(nblk), dim3(256),
                                   args, 0, stream);
    } else {
        // fallback: fp32 GEMM (R1-style, known-correct) + standalone circuit
        float* com = (float*)d_ws;               // 2 MB
        dim3 g(16, 16);
        gemm_f32<<<g, 256, 0, stream>>>(x, W, bias, com);
        circuit_sa<<<1024, 256, 0, stream>>>(com, x, qp, out);
    }
}

// Round 12
// 166.793 us; speedup vs baseline: 1.9396x; 1.9396x over previous
//
#include <hip/hip_runtime.h>
#include <math.h>

#define RS2f 0.70710678118654752f

typedef __attribute__((ext_vector_type(8))) short bf16x8;
typedef __attribute__((ext_vector_type(4))) float f32x4;

__device__ __forceinline__ unsigned short f2bf(float f) {
    unsigned u = __float_as_uint(f);
    unsigned r = (u + 0x7fffu + ((u >> 16) & 1u)) >> 16;   // RNE
    return (unsigned short)r;
}
__device__ __forceinline__ float bf2f(unsigned short h) {
    return __uint_as_float(((unsigned)h) << 16);
}

// ==================================================================
// Fused convert: x (1024x2048) and W (512x2048) fp32 -> bf16 hi/lo
// concat along K (row stride 4096 = [hi | lo]).  ~24 MB traffic, ~5us.
// ==================================================================
__global__ __launch_bounds__(256) void split_all(const float* __restrict__ x,
                                                 const float* __restrict__ W,
                                                 unsigned short* __restrict__ xc,
                                                 unsigned short* __restrict__ wc) {
    int idx = blockIdx.x * 256 + threadIdx.x;      // 786432 total
    const float* src; unsigned short* dst;
    if (idx < 524288) { src = x; dst = xc; }
    else              { idx -= 524288; src = W; dst = wc; }
    int m = idx >> 9;
    int c4 = (idx & 511) << 2;
    const float4 v = *(const float4*)&src[m * 2048 + c4];
    ushort4 hi, lo;
    hi.x = f2bf(v.x); lo.x = f2bf(v.x - bf2f(hi.x));
    hi.y = f2bf(v.y); lo.y = f2bf(v.y - bf2f(hi.y));
    hi.z = f2bf(v.z); lo.z = f2bf(v.z - bf2f(hi.z));
    hi.w = f2bf(v.w); lo.w = f2bf(v.w - bf2f(hi.w));
    *(ushort4*)&dst[m * 4096 + c4] = hi;
    *(ushort4*)&dst[m * 4096 + 2048 + c4] = lo;
}

// ==================================================================
// MFMA GEMM (R7 verbatim -- best measured gemm config, ~47us):
// com[m][n] = sum_k xc[m][k] wc[n][k] + bias[n].
// M=1024,N=512,K=4096 bf16, SK=1, direct com write. Block tile
// 64(M)x32(N), BK=64, 4 waves, 16x16x32 MFMA, ds_read_b128 frags
// from padded K-major tiles (stride 72 -> 2-way banks = free).
// Grid (16,16) = 256 blocks.
// ==================================================================
__global__ __launch_bounds__(256) void gemm_mfma(const unsigned short* __restrict__ A,  // 1024x4096
                                                 const unsigned short* __restrict__ B,  // 512x4096
                                                 const float* __restrict__ bias,
                                                 float* __restrict__ C) {               // 1024x512
    __shared__ short As[64 * 72];
    __shared__ short Bs[32 * 72];
    const int tid = threadIdx.x;
    const int lane = tid & 63;
    const int wv = tid >> 6;
    const int m0 = blockIdx.x * 64;
    const int n0 = blockIdx.y * 32;
    const int quad = lane >> 4, mrow = lane & 15;
    const int srow = tid >> 3;            // 0..31
    const int sk8 = (tid & 7) * 8;        // 0..56
    f32x4 acc0 = {0.f, 0.f, 0.f, 0.f};
    f32x4 acc1 = {0.f, 0.f, 0.f, 0.f};
    for (int k0 = 0; k0 < 4096; k0 += 64) {
        float4 a0 = *(const float4*)&A[(size_t)(m0 + srow) * 4096 + k0 + sk8];
        float4 a1 = *(const float4*)&A[(size_t)(m0 + srow + 32) * 4096 + k0 + sk8];
        float4 b0 = *(const float4*)&B[(size_t)(n0 + srow) * 4096 + k0 + sk8];
        __syncthreads();
        *(float4*)&As[srow * 72 + sk8] = a0;
        *(float4*)&As[(srow + 32) * 72 + sk8] = a1;
        *(float4*)&Bs[srow * 72 + sk8] = b0;
        __syncthreads();
        #pragma unroll
        for (int ks = 0; ks < 2; ++ks) {
            bf16x8 af  = *(const bf16x8*)&As[(wv * 16 + mrow) * 72 + ks * 32 + quad * 8];
            bf16x8 bf0 = *(const bf16x8*)&Bs[mrow * 72 + ks * 32 + quad * 8];
            bf16x8 bf1 = *(const bf16x8*)&Bs[(16 + mrow) * 72 + ks * 32 + quad * 8];
            acc0 = __builtin_amdgcn_mfma_f32_16x16x32_bf16(af, bf0, acc0, 0, 0, 0);
            acc1 = __builtin_amdgcn_mfma_f32_16x16x32_bf16(af, bf1, acc1, 0, 0, 0);
        }
    }
    // C/D layout: col = lane&15, row = quad*4 + r
    const float bv0 = bias[n0 + mrow];
    const float bv1 = bias[n0 + 16 + mrow];
    #pragma unroll
    for (int r = 0; r < 4; ++r) {
        int m = m0 + wv * 16 + quad * 4 + r;
        C[m * 512 + n0 + mrow]      = acc0[r] + bv0;
        C[m * 512 + n0 + 16 + mrow] = acc1[r] + bv1;
    }
}

// ==================== circuit helpers (R5/R8 structure, 77us measured) ====================
struct CMat { float m00r,m00i,m01r,m01i,m10r,m10i,m11r,m11i; };

__device__ __forceinline__ CMat mk_rot(const float* __restrict__ qp, int l, int w) {
    const float* g = qp + (l * 12 + w) * 3;
    float phi = g[0], th = g[1], om = g[2];
    float st, ct, sa, ca, sb, cb;
    sincosf(0.5f * th, &st, &ct);
    sincosf(0.5f * (phi + om), &sa, &ca);
    sincosf(0.5f * (phi - om), &sb, &cb);
    CMat M;
    M.m00r =  ct * ca; M.m00i = -ct * sa;
    M.m01r = -st * cb; M.m01i = -st * sb;
    M.m10r =  st * cb; M.m10i = -st * sb;
    M.m11r =  ct * ca; M.m11i =  ct * sa;
    return M;
}

template<int W> struct WI {
    static constexpr int kind = (W == 0 || W == 7) ? 2 : ((W >= 1 && W <= 6) ? 1 : 0);
    static constexpr int eb   = (W >= 8) ? (11 - W) : 0;
    static constexpr int lm   = (W >= 1 && W <= 6) ? (1 << (6 - W)) : 0;
    static constexpr int vm   = (W == 0) ? 2 : ((W == 7) ? 1 : 0);
};

__device__ __forceinline__ void exch_put(float* xbuf, int slot,
                                         const float vr[16], const float vi[16]) {
    __syncthreads();
    float4* p = (float4*)xbuf;
    #pragma unroll
    for (int j = 0; j < 8; ++j)
        p[(j << 8) + slot] = make_float4(vr[2*j], vi[2*j], vr[2*j+1], vi[2*j+1]);
    __syncthreads();
}

__device__ __forceinline__ void shfl_perm(float vr[16], float vi[16], int src) {
    #pragma unroll
    for (int e = 0; e < 16; ++e) {
        vr[e] = __shfl(vr[e], src, 64);
        vi[e] = __shfl(vi[e], src, 64);
    }
}

template<int EB>
__device__ __forceinline__ void rot_local(float vr[16], float vi[16], const CMat& M) {
    #pragma unroll
    for (int e = 0; e < 16; ++e) if (!(e & (1 << EB))) {
        const int e1 = e | (1 << EB);
        float x0r = vr[e],  x0i = vi[e];
        float x1r = vr[e1], x1i = vi[e1];
        vr[e]  = M.m00r*x0r - M.m00i*x0i + M.m01r*x1r - M.m01i*x1i;
        vi[e]  = M.m00r*x0i + M.m00i*x0r + M.m01r*x1i + M.m01i*x1r;
        vr[e1] = M.m10r*x0r - M.m10i*x0i + M.m11r*x1r - M.m11i*x1i;
        vi[e1] = M.m10r*x0i + M.m10i*x0r + M.m11r*x1i + M.m11i*x1r;
    }
}

template<int LM>
__device__ __forceinline__ void rot_lane(float vr[16], float vi[16], int lane, const CMat& M) {
    const bool hi = lane & LM;
    const float Ar = hi ? M.m11r : M.m00r, Ai = hi ? M.m11i : M.m00i;
    const float Br = hi ? M.m10r : M.m01r, Bi = hi ? M.m10i : M.m01i;
    #pragma unroll
    for (int e = 0; e < 16; ++e) {
        float pr = __shfl_xor(vr[e], LM, 64);
        float pi = __shfl_xor(vi[e], LM, 64);
        float orr = vr[e], oi = vi[e];
        vr[e] = Ar*orr - Ai*oi + Br*pr - Bi*pi;
        vi[e] = Ar*oi + Ai*orr + Br*pi + Bi*pr;
    }
}

template<int VM>
__device__ __forceinline__ void rot_wave(float vr[16], float vi[16], float* xbuf,
                                         int waveId, int lane, const CMat& M) {
    exch_put(xbuf, (waveId << 6) + lane, vr, vi);
    const float4* p = (const float4*)xbuf;
    const int ps = ((waveId ^ VM) << 6) + lane;
    const bool hi = waveId & VM;
    const float Ar = hi ? M.m11r : M.m00r, Ai = hi ? M.m11i : M.m00i;
    const float Br = hi ? M.m10r : M.m01r, Bi = hi ? M.m10i : M.m01i;
    #pragma unroll
    for (int j = 0; j < 8; ++j) {
        float4 q = p[(j << 8) + ps];
        const int e0 = 2*j, e1 = 2*j + 1;
        float r0 = vr[e0], i0 = vi[e0], r1 = vr[e1], i1 = vi[e1];
        vr[e0] = Ar*r0 - Ai*i0 + Br*q.x - Bi*q.y;
        vi[e0] = Ar*i0 + Ai*r0 + Br*q.y + Bi*q.x;
        vr[e1] = Ar*r1 - Ai*i1 + Br*q.z - Bi*q.w;
        vi[e1] = Ar*i1 + Ai*r1 + Br*q.w + Bi*q.z;
    }
}

template<int W>
__device__ __forceinline__ void rot_wire(float vr[16], float vi[16], float* xbuf,
                                         int waveId, int lane, const CMat& M) {
    if constexpr (WI<W>::kind == 0)      rot_local<WI<W>::eb>(vr, vi, M);
    else if constexpr (WI<W>::kind == 1) rot_lane<WI<W>::lm>(vr, vi, lane, M);
    else                                 rot_wave<WI<W>::vm>(vr, vi, xbuf, waveId, lane, M);
}

template<int C, int T>
__device__ __forceinline__ void cnot(float vr[16], float vi[16], float* xbuf,
                                     int waveId, int lane) {
    constexpr int ck = WI<C>::kind, tk = WI<T>::kind;
    if constexpr (ck == 0 && tk == 0) {
        constexpr int cb = 1 << WI<C>::eb, tb = 1 << WI<T>::eb;
        #pragma unroll
        for (int e = 0; e < 16; ++e) if ((e & cb) && !(e & tb)) {
            const int e1 = e | tb;
            float t = vr[e]; vr[e] = vr[e1]; vr[e1] = t;
            t = vi[e]; vi[e] = vi[e1]; vi[e1] = t;
        }
    } else if constexpr (ck == 0 && tk == 1) {
        constexpr int cb = 1 << WI<C>::eb, tm = WI<T>::lm;
        #pragma unroll
        for (int e = 0; e < 16; ++e) if (e & cb) {
            vr[e] = __shfl_xor(vr[e], tm, 64);
            vi[e] = __shfl_xor(vi[e], tm, 64);
        }
    } else if constexpr (ck == 0 && tk == 2) {
        constexpr int cb = 1 << WI<C>::eb, vm = WI<T>::vm;
        exch_put(xbuf, (waveId << 6) + lane, vr, vi);
        const float4* p = (const float4*)xbuf;
        const int ps = ((waveId ^ vm) << 6) + lane;
        #pragma unroll
        for (int j = 0; j < 8; ++j) {
            if ((((2*j) & cb) != 0) || (((2*j+1) & cb) != 0)) {
                float4 q = p[(j << 8) + ps];
                if (((2*j) & cb) != 0)   { vr[2*j]   = q.x; vi[2*j]   = q.y; }
                if (((2*j+1) & cb) != 0) { vr[2*j+1] = q.z; vi[2*j+1] = q.w; }
            }
        }
    } else if constexpr (ck == 1 && tk == 0) {
        constexpr int cm = WI<C>::lm, tb = 1 << WI<T>::eb;
        const bool cc = lane & cm;
        #pragma unroll
        for (int e = 0; e < 16; ++e) if (!(e & tb)) {
            const int e1 = e | tb;
            float a = vr[e], bb = vr[e1];
            vr[e] = cc ? bb : a; vr[e1] = cc ? a : bb;
            a = vi[e]; bb = vi[e1];
            vi[e] = cc ? bb : a; vi[e1] = cc ? a : bb;
        }
    } else if constexpr (ck == 1 && tk == 1) {
        constexpr int cm = WI<C>::lm, tm = WI<T>::lm;
        const int src = (lane & cm) ? (lane ^ tm) : lane;
        shfl_perm(vr, vi, src);
    } else if constexpr (ck == 1 && tk == 2) {
        constexpr int cm = WI<C>::lm, vm = WI<T>::vm;
        exch_put(xbuf, (waveId << 6) + lane, vr, vi);
        const float4* p = (const float4*)xbuf;
        const int ps = ((waveId ^ vm) << 6) + lane;
        const bool take = lane & cm;
        #pragma unroll
        for (int j = 0; j < 8; ++j) {
            float4 q = p[(j << 8) + ps];
            vr[2*j]   = take ? q.x : vr[2*j];   vi[2*j]   = take ? q.y : vi[2*j];
            vr[2*j+1] = take ? q.z : vr[2*j+1]; vi[2*j+1] = take ? q.w : vi[2*j+1];
        }
    } else if constexpr (ck == 2 && tk == 0) {
        constexpr int vm = WI<C>::vm, tb = 1 << WI<T>::eb;
        if (waveId & vm) {
            #pragma unroll
            for (int e = 0; e < 16; ++e) if (!(e & tb)) {
                const int e1 = e | tb;
                float t = vr[e]; vr[e] = vr[e1]; vr[e1] = t;
                t = vi[e]; vi[e] = vi[e1]; vi[e1] = t;
            }
        }
    } else {
        constexpr int vm = WI<C>::vm, tm = WI<T>::lm;
        if (waveId & vm) {
            #pragma unroll
            for (int e = 0; e < 16; ++e) {
                vr[e] = __shfl_xor(vr[e], tm, 64);
                vi[e] = __shfl_xor(vi[e], tm, 64);
            }
        }
    }
}

template<int W>
__device__ __forceinline__ void h_wire(float vr[16], float vi[16], float* xbuf,
                                       int waveId, int lane) {
    if constexpr (WI<W>::kind == 0) {
        constexpr int tb = 1 << WI<W>::eb;
        #pragma unroll
        for (int e = 0; e < 16; ++e) if (!(e & tb)) {
            const int e1 = e | tb;
            float x0 = vr[e], x1 = vr[e1];
            vr[e] = (x0 + x1) * RS2f; vr[e1] = (x0 - x1) * RS2f;
            x0 = vi[e]; x1 = vi[e1];
            vi[e] = (x0 + x1) * RS2f; vi[e1] = (x0 - x1) * RS2f;
        }
    } else if constexpr (WI<W>::kind == 1) {
        constexpr int m = WI<W>::lm;
        const float sgn = (lane & m) ? -RS2f : RS2f;
        #pragma unroll
        for (int e = 0; e < 16; ++e) {
            float pr = __shfl_xor(vr[e], m, 64);
            float pi = __shfl_xor(vi[e], m, 64);
            vr[e] = pr * RS2f + vr[e] * sgn;
            vi[e] = pi * RS2f + vi[e] * sgn;
        }
    } else {
        constexpr int vm = WI<W>::vm;
        exch_put(xbuf, (waveId << 6) + lane, vr, vi);
        const float4* p = (const float4*)xbuf;
        const int ps = ((waveId ^ vm) << 6) + lane;
        const float sgn = (waveId & vm) ? -RS2f : RS2f;
        #pragma unroll
        for (int j = 0; j < 8; ++j) {
            float4 q = p[(j << 8) + ps];
            vr[2*j]   = q.x * RS2f + vr[2*j]   * sgn;
            vi[2*j]   = q.y * RS2f + vi[2*j]   * sgn;
            vr[2*j+1] = q.z * RS2f + vr[2*j+1] * sgn;
            vi[2*j+1] = q.w * RS2f + vi[2*j+1] * sgn;
        }
    }
}

// ==================================================================
// 12-qubit circuit — EXACT R5/R8 structure (77us measured local opt).
//   idx = (w1<<11) | (lane<<5) | (w0<<4) | e,  waveId = (w1<<1)|w0
// ==================================================================
__global__ __launch_bounds__(256) void circuit_sa(const float* __restrict__ com,
                                                  const float* __restrict__ xf,
                                                  const float* __restrict__ qp,
                                                  float* __restrict__ out) {
    __shared__ float xbuf[8192];         // 32 KB exchange buffer
    __shared__ float ang[2048];          // 8 KB: com row, later xf row
    const int tid = threadIdx.x, lane = tid & 63, waveId = tid >> 6;
    const int b = blockIdx.x;
    if (tid < 128) ((float4*)ang)[tid] = ((const float4*)(com + b * 512))[tid];
    __syncthreads();
    float vr[16], vi[16];
    #pragma unroll
    for (int e = 0; e < 16; ++e) { vr[e] = 0.0f; vi[e] = 0.0f; }
    const float K9 = 0.044194173824159216f;   // 2^-4.5
    #pragma unroll
    for (int m = 0; m < 4; ++m) {
        int j = (lane << 3) | ((waveId & 1) << 2) | m;
        int rj = (int)(__brev((unsigned)j) >> 23);
        float s, c;
        sincosf(0.5f * ang[rj], &s, &c);
        vr[m << 2] = K9 * ((waveId & 2) ? s : c);
    }
    #pragma unroll 1
    for (int l = 0; l < 2; ++l) {
        { CMat M = mk_rot(qp, l, 0);  rot_wire<0 >(vr, vi, xbuf, waveId, lane, M); }
        { CMat M = mk_rot(qp, l, 1);  rot_wire<1 >(vr, vi, xbuf, waveId, lane, M); }
        { CMat M = mk_rot(qp, l, 2);  rot_wire<2 >(vr, vi, xbuf, waveId, lane, M); }
        { CMat M = mk_rot(qp, l, 3);  rot_wire<3 >(vr, vi, xbuf, waveId, lane, M); }
        { CMat M = mk_rot(qp, l, 4);  rot_wire<4 >(vr, vi, xbuf, waveId, lane, M); }
        { CMat M = mk_rot(qp, l, 5);  rot_wire<5 >(vr, vi, xbuf, waveId, lane, M); }
        { CMat M = mk_rot(qp, l, 6);  rot_wire<6 >(vr, vi, xbuf, waveId, lane, M); }
        { CMat M = mk_rot(qp, l, 7);  rot_wire<7 >(vr, vi, xbuf, waveId, lane, M); }
        { CMat M = mk_rot(qp, l, 8);  rot_wire<8 >(vr, vi, xbuf, waveId, lane, M); }
        { CMat M = mk_rot(qp, l, 9);  rot_wire<9 >(vr, vi, xbuf, waveId, lane, M); }
        { CMat M = mk_rot(qp, l, 10); rot_wire<10>(vr, vi, xbuf, waveId, lane, M); }
        { CMat M = mk_rot(qp, l, 11); rot_wire<11>(vr, vi, xbuf, waveId, lane, M); }
        if (l == 0) {                 // r = 1
            int j = lane;
            j ^= (j & 2)  ? 1  : 0;           // C(5,6)
            j ^= (j & 4)  ? 2  : 0;           // C(4,5)
            j ^= (j & 8)  ? 4  : 0;           // C(3,4)
            j ^= (j & 16) ? 8  : 0;           // C(2,3)
            j ^= (j & 32) ? 16 : 0;           // C(1,2)
            j ^= (waveId & 2) ? 32 : 0;       // C(0,1)
            shfl_perm(vr, vi, j);
            cnot<6,7>(vr,vi,xbuf,waveId,lane);   cnot<7,8>(vr,vi,xbuf,waveId,lane);
            cnot<8,9>(vr,vi,xbuf,waveId,lane);   cnot<9,10>(vr,vi,xbuf,waveId,lane);
            cnot<10,11>(vr,vi,xbuf,waveId,lane); cnot<11,0>(vr,vi,xbuf,waveId,lane);
        } else {                      // r = 2
            int j = lane;
            j ^= (j & 4)  ? 1  : 0;           // C(4,6)
            j ^= (j & 8)  ? 2  : 0;           // C(3,5)
            j ^= (j & 16) ? 4  : 0;           // C(2,4)
            j ^= (j & 32) ? 8  : 0;           // C(1,3)
            j ^= (waveId & 2) ? 16 : 0;       // C(0,2)
            shfl_perm(vr, vi, j);
            cnot<5,7>(vr,vi,xbuf,waveId,lane);   cnot<6,8>(vr,vi,xbuf,waveId,lane);
            cnot<7,9>(vr,vi,xbuf,waveId,lane);   cnot<8,10>(vr,vi,xbuf,waveId,lane);
            cnot<9,11>(vr,vi,xbuf,waveId,lane);  cnot<10,0>(vr,vi,xbuf,waveId,lane);
            cnot<11,1>(vr,vi,xbuf,waveId,lane);
        }
    }
    h_wire<1>(vr,vi,xbuf,waveId,lane);  h_wire<2>(vr,vi,xbuf,waveId,lane);
    h_wire<3>(vr,vi,xbuf,waveId,lane);  h_wire<4>(vr,vi,xbuf,waveId,lane);
    h_wire<5>(vr,vi,xbuf,waveId,lane);  h_wire<6>(vr,vi,xbuf,waveId,lane);
    h_wire<7>(vr,vi,xbuf,waveId,lane);  h_wire<8>(vr,vi,xbuf,waveId,lane);
    h_wire<9>(vr,vi,xbuf,waveId,lane);  h_wire<10>(vr,vi,xbuf,waveId,lane);
    h_wire<11>(vr,vi,xbuf,waveId,lane);
    {
        const float4* x4 = (const float4*)(xf + b * 2048);
        ((float4*)ang)[tid]       = x4[tid];
        ((float4*)ang)[tid + 256] = x4[tid + 256];
    }
    __syncthreads();
    exch_put(xbuf, (waveId << 6) + lane, vr, vi);
    {
        const float4* p = (const float4*)xbuf;
        const int ps = ((waveId ^ 2) << 6) + lane;
        const bool hi = waveId & 2;
        float acc = 0.0f;
        #pragma unroll
        for (int j = 0; j < 8; ++j) {
            float4 q = p[(j << 8) + ps];
            #pragma unroll
            for (int h = 0; h < 2; ++h) {
                const int e = 2*j + h;
                const float prr = h ? q.z : q.x;
                const float pii = h ? q.w : q.y;
                int v = (lane << 5) | ((waveId & 1) << 4) | e;
                int rv = (int)(__brev((unsigned)v) >> 21);
                float s, c;
                sincosf(0.5f * ang[rv], &s, &c);
                float nr = hi ? (s*prr + c*vr[e]) : (c*vr[e] - s*prr);
                float ni = hi ? (s*pii + c*vi[e]) : (c*vi[e] - s*pii);
                acc += nr*nr + ni*ni;
            }
        }
        if (!hi) acc = -acc;
        #pragma unroll
        for (int off = 32; off > 0; off >>= 1) acc += __shfl_down(acc, off, 64);
        __syncthreads();
        if (lane == 0) xbuf[waveId] = acc;
        __syncthreads();
        if (tid == 0) out[b] = xbuf[0] + xbuf[1] + xbuf[2] + xbuf[3];
    }
}

// ==================== fallback (small ws): fp32 GEMM + circuit ====================
__global__ __launch_bounds__(256) void gemm_f32(const float* __restrict__ A,
                                                const float* __restrict__ W,
                                                const float* __restrict__ bias,
                                                float* __restrict__ C) {
    __shared__ float Asf[64][33];
    __shared__ float Bsf[32][33];
    const int tid = threadIdx.x;
    const int m0 = blockIdx.x * 64;
    const int n0 = blockIdx.y * 32;
    const int tm = tid >> 4, tn = tid & 15;
    float acc[4][2] = {};
    for (int k0 = 0; k0 < 2048; k0 += 32) {
        #pragma unroll
        for (int i = 0; i < 8; ++i) {
            int idx = tid + i * 256;
            Asf[idx >> 5][idx & 31] = A[(m0 + (idx >> 5)) * 2048 + k0 + (idx & 31)];
        }
        #pragma unroll
        for (int i = 0; i < 4; ++i) {
            int idx = tid + i * 256;
            Bsf[idx >> 5][idx & 31] = W[(n0 + (idx >> 5)) * 2048 + k0 + (idx & 31)];
        }
        __syncthreads();
        #pragma unroll
        for (int kk = 0; kk < 32; ++kk) {
            float a0 = Asf[tm*4+0][kk], a1 = Asf[tm*4+1][kk];
            float a2 = Asf[tm*4+2][kk], a3 = Asf[tm*4+3][kk];
            float b0 = Bsf[tn*2+0][kk], b1 = Bsf[tn*2+1][kk];
            acc[0][0] += a0*b0; acc[0][1] += a0*b1;
            acc[1][0] += a1*b0; acc[1][1] += a1*b1;
            acc[2][0] += a2*b0; acc[2][1] += a2*b1;
            acc[3][0] += a3*b0; acc[3][1] += a3*b1;
        }
        __syncthreads();
    }
    #pragma unroll
    for (int r = 0; r < 4; ++r)
        #pragma unroll
        for (int c = 0; c < 2; ++c)
            C[(m0 + tm*4 + r) * 512 + n0 + tn*2 + c] = acc[r][c] + bias[n0 + tn*2 + c];
}

extern "C" void kernel_launch(void* const* d_in, const int* in_sizes, int n_in,
                              void* d_out, int out_size, void* d_ws, size_t ws_size,
                              hipStream_t stream) {
    const float* x    = (const float*)d_in[0];   // (1024,2048)
    const float* W    = (const float*)d_in[1];   // (512,2048)
    const float* bias = (const float*)d_in[2];   // (512,)
    const float* qp   = (const float*)d_in[3];   // (2,12,3)
    float* out = (float*)d_out;                  // (1024,)

    const size_t MB = 1024ull * 1024;
    if (ws_size >= 14 * MB) {
        // ws: xc 8MB | wc 4MB | com 2MB
        unsigned short* xc = (unsigned short*)d_ws;
        unsigned short* wc = (unsigned short*)((char*)d_ws + 8 * MB);
        float* com = (float*)((char*)d_ws + 12 * MB);
        split_all<<<3072, 256, 0, stream>>>(x, W, xc, wc);
        dim3 g(16, 16);                          // 64x32 tiles, 256 blocks
        gemm_mfma<<<g, 256, 0, stream>>>(xc, wc, bias, com);
        circuit_sa<<<1024, 256, 0, stream>>>(com, x, qp, out);
    } else {
        float* com = (float*)d_ws;               // 2 MB
        dim3 g(16, 16);
        gemm_f32<<<g, 256, 0, stream>>>(x, W, bias, com);
        circuit_sa<<<1024, 256, 0, stream>>>(com, x, qp, out);
    }
}

// Round 13
// 149.603 us; speedup vs baseline: 2.1625x; 1.1149x over previous
//
#include <hip/hip_runtime.h>
#include <math.h>

#define RS2f 0.70710678118654752f

typedef __attribute__((ext_vector_type(8))) short bf16x8;
typedef __attribute__((ext_vector_type(4))) float f32x4;

__device__ __forceinline__ unsigned short f2bf(float f) {
    unsigned u = __float_as_uint(f);
    unsigned r = (u + 0x7fffu + ((u >> 16) & 1u)) >> 16;   // RNE
    return (unsigned short)r;
}
__device__ __forceinline__ float bf2f(unsigned short h) {
    return __uint_as_float(((unsigned)h) << 16);
}

// ==================================================================
// Fused convert: x (1024x2048) and W (512x2048) fp32 -> bf16 hi/lo
// concat along K (row stride 4096 = [hi | lo]).  ~24 MB traffic.
// ==================================================================
__global__ __launch_bounds__(256) void split_all(const float* __restrict__ x,
                                                 const float* __restrict__ W,
                                                 unsigned short* __restrict__ xc,
                                                 unsigned short* __restrict__ wc) {
    int idx = blockIdx.x * 256 + threadIdx.x;      // 786432 total
    const float* src; unsigned short* dst;
    if (idx < 524288) { src = x; dst = xc; }
    else              { idx -= 524288; src = W; dst = wc; }
    int m = idx >> 9;
    int c4 = (idx & 511) << 2;
    const float4 v = *(const float4*)&src[m * 2048 + c4];
    ushort4 hi, lo;
    hi.x = f2bf(v.x); lo.x = f2bf(v.x - bf2f(hi.x));
    hi.y = f2bf(v.y); lo.y = f2bf(v.y - bf2f(hi.y));
    hi.z = f2bf(v.z); lo.z = f2bf(v.z - bf2f(hi.z));
    hi.w = f2bf(v.w); lo.w = f2bf(v.w - bf2f(hi.w));
    *(ushort4*)&dst[m * 4096 + c4] = hi;
    *(ushort4*)&dst[m * 4096 + 2048 + c4] = lo;
}

// ==================================================================
// MFMA GEMM partials (R10 structure: 64x64 tile, BK=64, 4 waves,
// SK=8 -> grid 1024 = 4 blocks/CU) with ONE change: staging now uses
// __builtin_amdgcn_global_load_lds width=16 (direct TA->LDS deposit,
// no VGPR round trip, no ds_writes). LDS dest is wave-uniform base +
// lane*16 -> unpadded 64-short rows with XOR segment swizzle:
//   row r, global seg g (16B) stored at seg g^(r&7); reads apply the
//   same XOR -> 2-way bank aliasing (free, m136).
// ==================================================================
__global__ __launch_bounds__(256) void gemm64(const unsigned short* __restrict__ A,  // 1024x4096
                                              const unsigned short* __restrict__ B,  // 512x4096
                                              float* __restrict__ P, int nch) {
    __shared__ short As[64 * 64];        // 8 KB, unpadded
    __shared__ short Bs[64 * 64];        // 8 KB
    const int tid = threadIdx.x, lane = tid & 63, wv = tid >> 6;
    const int quad = lane >> 4, mrow = lane & 15;
    const int m0 = blockIdx.x * 64, n0 = blockIdx.y * 64;
    const int kb = blockIdx.z * nch * 64;
    const int lrow = lane >> 3;                 // 0..7 row within group
    const int gseg = (lane & 7) ^ lrow;         // swizzled global segment

    f32x4 acc[4];
    #pragma unroll
    for (int j = 0; j < 4; ++j) acc[j] = (f32x4){0.f, 0.f, 0.f, 0.f};

    for (int ch = 0; ch < nch; ++ch) {
        const int ko = kb + ch * 64;
        #pragma unroll
        for (int t = 0; t < 2; ++t) {           // 2 row-groups of 8 per wave
            const int ra = (wv * 2 + t) * 8;
            const unsigned short* ga = A + (size_t)(m0 + ra + lrow) * 4096 + ko + gseg * 8;
            const unsigned short* gb = B + (size_t)(n0 + ra + lrow) * 4096 + ko + gseg * 8;
            __builtin_amdgcn_global_load_lds(
                (const __attribute__((address_space(1))) void*)ga,
                (__attribute__((address_space(3))) void*)(As + ra * 64), 16, 0, 0);
            __builtin_amdgcn_global_load_lds(
                (const __attribute__((address_space(1))) void*)gb,
                (__attribute__((address_space(3))) void*)(Bs + ra * 64), 16, 0, 0);
        }
        __syncthreads();                        // drains vmcnt -> deposits visible
        #pragma unroll
        for (int ks = 0; ks < 2; ++ks) {
            const int q = ks * 4 + quad;        // k-segment 0..7
            const int am = wv * 16 + mrow;
            bf16x8 af = *(const bf16x8*)&As[am * 64 + ((q ^ (am & 7)) << 3)];
            #pragma unroll
            for (int j = 0; j < 4; ++j) {
                const int bn = j * 16 + mrow;
                bf16x8 bf = *(const bf16x8*)&Bs[bn * 64 + ((q ^ (bn & 7)) << 3)];
                acc[j] = __builtin_amdgcn_mfma_f32_16x16x32_bf16(af, bf, acc[j], 0, 0, 0);
            }
        }
        __syncthreads();                        // all reads done before next deposit
    }
    // C/D layout: col = lane&15, row = quad*4 + r
    float* Pz = P + (size_t)blockIdx.z * 524288;
    #pragma unroll
    for (int j = 0; j < 4; ++j)
        #pragma unroll
        for (int r = 0; r < 4; ++r)
            Pz[(m0 + wv * 16 + quad * 4 + r) * 512 + n0 + j * 16 + mrow] = acc[j][r];
}

// ==================================================================
// Fallback fp32 GEMM (small ws): writes raw product (no bias) to P;
// circuit adds bias via its fused reduce (SK=1).
// ==================================================================
__global__ __launch_bounds__(256) void gemm_f32(const float* __restrict__ A,
                                                const float* __restrict__ W,
                                                float* __restrict__ C) {
    __shared__ float Asf[64][33];
    __shared__ float Bsf[32][33];
    const int tid = threadIdx.x;
    const int m0 = blockIdx.x * 64;
    const int n0 = blockIdx.y * 32;
    const int tm = tid >> 4, tn = tid & 15;
    float acc[4][2] = {};
    for (int k0 = 0; k0 < 2048; k0 += 32) {
        #pragma unroll
        for (int i = 0; i < 8; ++i) {
            int idx = tid + i * 256;
            Asf[idx >> 5][idx & 31] = A[(m0 + (idx >> 5)) * 2048 + k0 + (idx & 31)];
        }
        #pragma unroll
        for (int i = 0; i < 4; ++i) {
            int idx = tid + i * 256;
            Bsf[idx >> 5][idx & 31] = W[(n0 + (idx >> 5)) * 2048 + k0 + (idx & 31)];
        }
        __syncthreads();
        #pragma unroll
        for (int kk = 0; kk < 32; ++kk) {
            float a0 = Asf[tm*4+0][kk], a1 = Asf[tm*4+1][kk];
            float a2 = Asf[tm*4+2][kk], a3 = Asf[tm*4+3][kk];
            float b0 = Bsf[tn*2+0][kk], b1 = Bsf[tn*2+1][kk];
            acc[0][0] += a0*b0; acc[0][1] += a0*b1;
            acc[1][0] += a1*b0; acc[1][1] += a1*b1;
            acc[2][0] += a2*b0; acc[2][1] += a2*b1;
            acc[3][0] += a3*b0; acc[3][1] += a3*b1;
        }
        __syncthreads();
    }
    #pragma unroll
    for (int r = 0; r < 4; ++r)
        #pragma unroll
        for (int c = 0; c < 2; ++c)
            C[(m0 + tm*4 + r) * 512 + n0 + tn*2 + c] = acc[r][c];
}

// ==================== circuit helpers (R5/R8 gate structure, 77us measured) ====================
struct CMat { float m00r,m00i,m01r,m01i,m10r,m10i,m11r,m11i; };

__device__ __forceinline__ CMat mk_rot(const float* __restrict__ qp, int l, int w) {
    const float* g = qp + (l * 12 + w) * 3;
    float phi = g[0], th = g[1], om = g[2];
    float st, ct, sa, ca, sb, cb;
    sincosf(0.5f * th, &st, &ct);
    sincosf(0.5f * (phi + om), &sa, &ca);
    sincosf(0.5f * (phi - om), &sb, &cb);
    CMat M;
    M.m00r =  ct * ca; M.m00i = -ct * sa;
    M.m01r = -st * cb; M.m01i = -st * sb;
    M.m10r =  st * cb; M.m10i = -st * sb;
    M.m11r =  ct * ca; M.m11i =  ct * sa;
    return M;
}

template<int W> struct WI {
    static constexpr int kind = (W == 0 || W == 7) ? 2 : ((W >= 1 && W <= 6) ? 1 : 0);
    static constexpr int eb   = (W >= 8) ? (11 - W) : 0;
    static constexpr int lm   = (W >= 1 && W <= 6) ? (1 << (6 - W)) : 0;
    static constexpr int vm   = (W == 0) ? 2 : ((W == 7) ? 1 : 0);
};

__device__ __forceinline__ void exch_put(float* xbuf, int slot,
                                         const float vr[16], const float vi[16]) {
    __syncthreads();
    float4* p = (float4*)xbuf;
    #pragma unroll
    for (int j = 0; j < 8; ++j)
        p[(j << 8) + slot] = make_float4(vr[2*j], vi[2*j], vr[2*j+1], vi[2*j+1]);
    __syncthreads();
}

__device__ __forceinline__ void shfl_perm(float vr[16], float vi[16], int src) {
    #pragma unroll
    for (int e = 0; e < 16; ++e) {
        vr[e] = __shfl(vr[e], src, 64);
        vi[e] = __shfl(vi[e], src, 64);
    }
}

template<int EB>
__device__ __forceinline__ void rot_local(float vr[16], float vi[16], const CMat& M) {
    #pragma unroll
    for (int e = 0; e < 16; ++e) if (!(e & (1 << EB))) {
        const int e1 = e | (1 << EB);
        float x0r = vr[e],  x0i = vi[e];
        float x1r = vr[e1], x1i = vi[e1];
        vr[e]  = M.m00r*x0r - M.m00i*x0i + M.m01r*x1r - M.m01i*x1i;
        vi[e]  = M.m00r*x0i + M.m00i*x0r + M.m01r*x1i + M.m01i*x1r;
        vr[e1] = M.m10r*x0r - M.m10i*x0i + M.m11r*x1r - M.m11i*x1i;
        vi[e1] = M.m10r*x0i + M.m10i*x0r + M.m11r*x1i + M.m11i*x1r;
    }
}

template<int LM>
__device__ __forceinline__ void rot_lane(float vr[16], float vi[16], int lane, const CMat& M) {
    const bool hi = lane & LM;
    const float Ar = hi ? M.m11r : M.m00r, Ai = hi ? M.m11i : M.m00i;
    const float Br = hi ? M.m10r : M.m01r, Bi = hi ? M.m10i : M.m01i;
    #pragma unroll
    for (int e = 0; e < 16; ++e) {
        float pr = __shfl_xor(vr[e], LM, 64);
        float pi = __shfl_xor(vi[e], LM, 64);
        float orr = vr[e], oi = vi[e];
        vr[e] = Ar*orr - Ai*oi + Br*pr - Bi*pi;
        vi[e] = Ar*oi + Ai*orr + Br*pi + Bi*pr;
    }
}

template<int VM>
__device__ __forceinline__ void rot_wave(float vr[16], float vi[16], float* xbuf,
                                         int waveId, int lane, const CMat& M) {
    exch_put(xbuf, (waveId << 6) + lane, vr, vi);
    const float4* p = (const float4*)xbuf;
    const int ps = ((waveId ^ VM) << 6) + lane;
    const bool hi = waveId & VM;
    const float Ar = hi ? M.m11r : M.m00r, Ai = hi ? M.m11i : M.m00i;
    const float Br = hi ? M.m10r : M.m01r, Bi = hi ? M.m10i : M.m01i;
    #pragma unroll
    for (int j = 0; j < 8; ++j) {
        float4 q = p[(j << 8) + ps];
        const int e0 = 2*j, e1 = 2*j + 1;
        float r0 = vr[e0], i0 = vi[e0], r1 = vr[e1], i1 = vi[e1];
        vr[e0] = Ar*r0 - Ai*i0 + Br*q.x - Bi*q.y;
        vi[e0] = Ar*i0 + Ai*r0 + Br*q.y + Bi*q.x;
        vr[e1] = Ar*r1 - Ai*i1 + Br*q.z - Bi*q.w;
        vi[e1] = Ar*i1 + Ai*r1 + Br*q.w + Bi*q.z;
    }
}

template<int W>
__device__ __forceinline__ void rot_wire(float vr[16], float vi[16], float* xbuf,
                                         int waveId, int lane, const CMat& M) {
    if constexpr (WI<W>::kind == 0)      rot_local<WI<W>::eb>(vr, vi, M);
    else if constexpr (WI<W>::kind == 1) rot_lane<WI<W>::lm>(vr, vi, lane, M);
    else                                 rot_wave<WI<W>::vm>(vr, vi, xbuf, waveId, lane, M);
}

template<int C, int T>
__device__ __forceinline__ void cnot(float vr[16], float vi[16], float* xbuf,
                                     int waveId, int lane) {
    constexpr int ck = WI<C>::kind, tk = WI<T>::kind;
    if constexpr (ck == 0 && tk == 0) {
        constexpr int cb = 1 << WI<C>::eb, tb = 1 << WI<T>::eb;
        #pragma unroll
        for (int e = 0; e < 16; ++e) if ((e & cb) && !(e & tb)) {
            const int e1 = e | tb;
            float t = vr[e]; vr[e] = vr[e1]; vr[e1] = t;
            t = vi[e]; vi[e] = vi[e1]; vi[e1] = t;
        }
    } else if constexpr (ck == 0 && tk == 1) {
        constexpr int cb = 1 << WI<C>::eb, tm = WI<T>::lm;
        #pragma unroll
        for (int e = 0; e < 16; ++e) if (e & cb) {
            vr[e] = __shfl_xor(vr[e], tm, 64);
            vi[e] = __shfl_xor(vi[e], tm, 64);
        }
    } else if constexpr (ck == 0 && tk == 2) {
        constexpr int cb = 1 << WI<C>::eb, vm = WI<T>::vm;
        exch_put(xbuf, (waveId << 6) + lane, vr, vi);
        const float4* p = (const float4*)xbuf;
        const int ps = ((waveId ^ vm) << 6) + lane;
        #pragma unroll
        for (int j = 0; j < 8; ++j) {
            if ((((2*j) & cb) != 0) || (((2*j+1) & cb) != 0)) {
                float4 q = p[(j << 8) + ps];
                if (((2*j) & cb) != 0)   { vr[2*j]   = q.x; vi[2*j]   = q.y; }
                if (((2*j+1) & cb) != 0) { vr[2*j+1] = q.z; vi[2*j+1] = q.w; }
            }
        }
    } else if constexpr (ck == 1 && tk == 0) {
        constexpr int cm = WI<C>::lm, tb = 1 << WI<T>::eb;
        const bool cc = lane & cm;
        #pragma unroll
        for (int e = 0; e < 16; ++e) if (!(e & tb)) {
            const int e1 = e | tb;
            float a = vr[e], bb = vr[e1];
            vr[e] = cc ? bb : a; vr[e1] = cc ? a : bb;
            a = vi[e]; bb = vi[e1];
            vi[e] = cc ? bb : a; vi[e1] = cc ? a : bb;
        }
    } else if constexpr (ck == 1 && tk == 1) {
        constexpr int cm = WI<C>::lm, tm = WI<T>::lm;
        const int src = (lane & cm) ? (lane ^ tm) : lane;
        shfl_perm(vr, vi, src);
    } else if constexpr (ck == 1 && tk == 2) {
        constexpr int cm = WI<C>::lm, vm = WI<T>::vm;
        exch_put(xbuf, (waveId << 6) + lane, vr, vi);
        const float4* p = (const float4*)xbuf;
        const int ps = ((waveId ^ vm) << 6) + lane;
        const bool take = lane & cm;
        #pragma unroll
        for (int j = 0; j < 8; ++j) {
            float4 q = p[(j << 8) + ps];
            vr[2*j]   = take ? q.x : vr[2*j];   vi[2*j]   = take ? q.y : vi[2*j];
            vr[2*j+1] = take ? q.z : vr[2*j+1]; vi[2*j+1] = take ? q.w : vi[2*j+1];
        }
    } else if constexpr (ck == 2 && tk == 0) {
        constexpr int vm = WI<C>::vm, tb = 1 << WI<T>::eb;
        if (waveId & vm) {
            #pragma unroll
            for (int e = 0; e < 16; ++e) if (!(e & tb)) {
                const int e1 = e | tb;
                float t = vr[e]; vr[e] = vr[e1]; vr[e1] = t;
                t = vi[e]; vi[e] = vi[e1]; vi[e1] = t;
            }
        }
    } else {
        constexpr int vm = WI<C>::vm, tm = WI<T>::lm;
        if (waveId & vm) {
            #pragma unroll
            for (int e = 0; e < 16; ++e) {
                vr[e] = __shfl_xor(vr[e], tm, 64);
                vi[e] = __shfl_xor(vi[e], tm, 64);
            }
        }
    }
}

template<int W>
__device__ __forceinline__ void h_wire(float vr[16], float vi[16], float* xbuf,
                                       int waveId, int lane) {
    if constexpr (WI<W>::kind == 0) {
        constexpr int tb = 1 << WI<W>::eb;
        #pragma unroll
        for (int e = 0; e < 16; ++e) if (!(e & tb)) {
            const int e1 = e | tb;
            float x0 = vr[e], x1 = vr[e1];
            vr[e] = (x0 + x1) * RS2f; vr[e1] = (x0 - x1) * RS2f;
            x0 = vi[e]; x1 = vi[e1];
            vi[e] = (x0 + x1) * RS2f; vi[e1] = (x0 - x1) * RS2f;
        }
    } else if constexpr (WI<W>::kind == 1) {
        constexpr int m = WI<W>::lm;
        const float sgn = (lane & m) ? -RS2f : RS2f;
        #pragma unroll
        for (int e = 0; e < 16; ++e) {
            float pr = __shfl_xor(vr[e], m, 64);
            float pi = __shfl_xor(vi[e], m, 64);
            vr[e] = pr * RS2f + vr[e] * sgn;
            vi[e] = pi * RS2f + vi[e] * sgn;
        }
    } else {
        constexpr int vm = WI<W>::vm;
        exch_put(xbuf, (waveId << 6) + lane, vr, vi);
        const float4* p = (const float4*)xbuf;
        const int ps = ((waveId ^ vm) << 6) + lane;
        const float sgn = (waveId & vm) ? -RS2f : RS2f;
        #pragma unroll
        for (int j = 0; j < 8; ++j) {
            float4 q = p[(j << 8) + ps];
            vr[2*j]   = q.x * RS2f + vr[2*j]   * sgn;
            vi[2*j]   = q.y * RS2f + vi[2*j]   * sgn;
            vr[2*j+1] = q.z * RS2f + vr[2*j+1] * sgn;
            vi[2*j+1] = q.w * RS2f + vi[2*j+1] * sgn;
        }
    }
}

// ==================================================================
// 12-qubit circuit — R10 version: R5/R8 gate structure + fused
// SK-slab reduce+bias in the com staging (81us measured at SK=8).
// ==================================================================
__global__ __launch_bounds__(256) void circuit_kernel(const float* __restrict__ P,
                                                      const float* __restrict__ bias,
                                                      const float* __restrict__ xf,
                                                      const float* __restrict__ qp,
                                                      float* __restrict__ out, int SK) {
    __shared__ float xbuf[8192];         // 32 KB exchange buffer
    __shared__ float ang[2048];          // 8 KB: com row, later xf row
    const int tid = threadIdx.x, lane = tid & 63, waveId = tid >> 6;
    const int b = blockIdx.x;

    if (tid < 128) {
        float4 s = ((const float4*)bias)[tid];
        for (int z = 0; z < SK; ++z) {
            float4 p4 = *(const float4*)&P[(size_t)z * 524288 + b * 512 + tid * 4];
            s.x += p4.x; s.y += p4.y; s.z += p4.z; s.w += p4.w;
        }
        ((float4*)ang)[tid] = s;
    }
    __syncthreads();

    float vr[16], vi[16];
    #pragma unroll
    for (int e = 0; e < 16; ++e) { vr[e] = 0.0f; vi[e] = 0.0f; }

    const float K9 = 0.044194173824159216f;   // 2^-4.5
    #pragma unroll
    for (int m = 0; m < 4; ++m) {
        int j = (lane << 3) | ((waveId & 1) << 2) | m;
        int rj = (int)(__brev((unsigned)j) >> 23);
        float s, c;
        sincosf(0.5f * ang[rj], &s, &c);
        vr[m << 2] = K9 * ((waveId & 2) ? s : c);
    }

    #pragma unroll 1
    for (int l = 0; l < 2; ++l) {
        { CMat M = mk_rot(qp, l, 0);  rot_wire<0 >(vr, vi, xbuf, waveId, lane, M); }
        { CMat M = mk_rot(qp, l, 1);  rot_wire<1 >(vr, vi, xbuf, waveId, lane, M); }
        { CMat M = mk_rot(qp, l, 2);  rot_wire<2 >(vr, vi, xbuf, waveId, lane, M); }
        { CMat M = mk_rot(qp, l, 3);  rot_wire<3 >(vr, vi, xbuf, waveId, lane, M); }
        { CMat M = mk_rot(qp, l, 4);  rot_wire<4 >(vr, vi, xbuf, waveId, lane, M); }
        { CMat M = mk_rot(qp, l, 5);  rot_wire<5 >(vr, vi, xbuf, waveId, lane, M); }
        { CMat M = mk_rot(qp, l, 6);  rot_wire<6 >(vr, vi, xbuf, waveId, lane, M); }
        { CMat M = mk_rot(qp, l, 7);  rot_wire<7 >(vr, vi, xbuf, waveId, lane, M); }
        { CMat M = mk_rot(qp, l, 8);  rot_wire<8 >(vr, vi, xbuf, waveId, lane, M); }
        { CMat M = mk_rot(qp, l, 9);  rot_wire<9 >(vr, vi, xbuf, waveId, lane, M); }
        { CMat M = mk_rot(qp, l, 10); rot_wire<10>(vr, vi, xbuf, waveId, lane, M); }
        { CMat M = mk_rot(qp, l, 11); rot_wire<11>(vr, vi, xbuf, waveId, lane, M); }
        if (l == 0) {                 // r = 1
            int j = lane;
            j ^= (j & 2)  ? 1  : 0;           // C(5,6)
            j ^= (j & 4)  ? 2  : 0;           // C(4,5)
            j ^= (j & 8)  ? 4  : 0;           // C(3,4)
            j ^= (j & 16) ? 8  : 0;           // C(2,3)
            j ^= (j & 32) ? 16 : 0;           // C(1,2)
            j ^= (waveId & 2) ? 32 : 0;       // C(0,1)
            shfl_perm(vr, vi, j);
            cnot<6,7>(vr,vi,xbuf,waveId,lane);   cnot<7,8>(vr,vi,xbuf,waveId,lane);
            cnot<8,9>(vr,vi,xbuf,waveId,lane);   cnot<9,10>(vr,vi,xbuf,waveId,lane);
            cnot<10,11>(vr,vi,xbuf,waveId,lane); cnot<11,0>(vr,vi,xbuf,waveId,lane);
        } else {                      // r = 2
            int j = lane;
            j ^= (j & 4)  ? 1  : 0;           // C(4,6)
            j ^= (j & 8)  ? 2  : 0;           // C(3,5)
            j ^= (j & 16) ? 4  : 0;           // C(2,4)
            j ^= (j & 32) ? 8  : 0;           // C(1,3)
            j ^= (waveId & 2) ? 16 : 0;       // C(0,2)
            shfl_perm(vr, vi, j);
            cnot<5,7>(vr,vi,xbuf,waveId,lane);   cnot<6,8>(vr,vi,xbuf,waveId,lane);
            cnot<7,9>(vr,vi,xbuf,waveId,lane);   cnot<8,10>(vr,vi,xbuf,waveId,lane);
            cnot<9,11>(vr,vi,xbuf,waveId,lane);  cnot<10,0>(vr,vi,xbuf,waveId,lane);
            cnot<11,1>(vr,vi,xbuf,waveId,lane);
        }
    }

    h_wire<1>(vr,vi,xbuf,waveId,lane);  h_wire<2>(vr,vi,xbuf,waveId,lane);
    h_wire<3>(vr,vi,xbuf,waveId,lane);  h_wire<4>(vr,vi,xbuf,waveId,lane);
    h_wire<5>(vr,vi,xbuf,waveId,lane);  h_wire<6>(vr,vi,xbuf,waveId,lane);
    h_wire<7>(vr,vi,xbuf,waveId,lane);  h_wire<8>(vr,vi,xbuf,waveId,lane);
    h_wire<9>(vr,vi,xbuf,waveId,lane);  h_wire<10>(vr,vi,xbuf,waveId,lane);
    h_wire<11>(vr,vi,xbuf,waveId,lane);

    {
        const float4* x4 = (const float4*)(xf + b * 2048);
        ((float4*)ang)[tid]       = x4[tid];
        ((float4*)ang)[tid + 256] = x4[tid + 256];
    }
    __syncthreads();

    exch_put(xbuf, (waveId << 6) + lane, vr, vi);
    {
        const float4* p = (const float4*)xbuf;
        const int ps = ((waveId ^ 2) << 6) + lane;
        const bool hi = waveId & 2;
        float acc = 0.0f;
        #pragma unroll
        for (int j = 0; j < 8; ++j) {
            float4 q = p[(j << 8) + ps];
            #pragma unroll
            for (int h = 0; h < 2; ++h) {
                const int e = 2*j + h;
                const float prr = h ? q.z : q.x;
                const float pii = h ? q.w : q.y;
                int v = (lane << 5) | ((waveId & 1) << 4) | e;
                int rv = (int)(__brev((unsigned)v) >> 21);
                float s, c;
                sincosf(0.5f * ang[rv], &s, &c);
                float nr = hi ? (s*prr + c*vr[e]) : (c*vr[e] - s*prr);
                float ni = hi ? (s*pii + c*vi[e]) : (c*vi[e] - s*pii);
                acc += nr*nr + ni*ni;
            }
        }
        if (!hi) acc = -acc;
        #pragma unroll
        for (int off = 32; off > 0; off >>= 1) acc += __shfl_down(acc, off, 64);
        __syncthreads();
        if (lane == 0) xbuf[waveId] = acc;
        __syncthreads();
        if (tid == 0) out[b] = xbuf[0] + xbuf[1] + xbuf[2] + xbuf[3];
    }
}

extern "C" void kernel_launch(void* const* d_in, const int* in_sizes, int n_in,
                              void* d_out, int out_size, void* d_ws, size_t ws_size,
                              hipStream_t stream) {
    const float* x    = (const float*)d_in[0];   // (1024,2048)
    const float* W    = (const float*)d_in[1];   // (512,2048)
    const float* bias = (const float*)d_in[2];   // (512,)
    const float* qp   = (const float*)d_in[3];   // (2,12,3)
    float* out = (float*)d_out;                  // (1024,)

    const size_t MB = 1024ull * 1024;
    const size_t BASE = 12 * MB;                 // xc 8MB + wc 4MB
    if (ws_size >= BASE + 4 * MB) {
        unsigned short* xc = (unsigned short*)d_ws;
        unsigned short* wc = (unsigned short*)((char*)d_ws + 8 * MB);
        float* P = (float*)((char*)d_ws + BASE);
        int SK;
        if      (ws_size >= BASE + 16 * MB) SK = 8;
        else if (ws_size >= BASE + 8 * MB)  SK = 4;
        else                                SK = 2;
        split_all<<<3072, 256, 0, stream>>>(x, W, xc, wc);
        dim3 g(16, 8, SK);                       // 64x64 tiles, split-K
        gemm64<<<g, 256, 0, stream>>>(xc, wc, P, 4096 / SK / 64);
        circuit_kernel<<<1024, 256, 0, stream>>>(P, bias, x, qp, out, SK);
    } else {
        float* P = (float*)d_ws;                 // 2 MB raw product
        dim3 g(16, 16);
        gemm_f32<<<g, 256, 0, stream>>>(x, W, P);
        circuit_kernel<<<1024, 256, 0, stream>>>(P, bias, x, qp, out, 1);
    }
}